// Round 6
// baseline (3325.995 us; speedup 1.0000x reference)
//
#include <hip/hip_runtime.h>

#define BQ 8
#define NPTS 16384
#define CFEAT 64
#define NPOINT 1024
#define NSAMPLE 32
#define RADIUS2 0.04f

typedef float v2f __attribute__((ext_vector_type(2)));

// ------------------------------------------------------------------
// Fused front kernel, 1024 threads/block:
//   blocks 0..7    : furthest point sampling (1 block per batch)
//   block  8       : weight transpose prep
//   blocks 9..1032 : features (B,C,N) -> featT (B,N,C) transpose
// FPS v4: round-4/5 post-mortem showed the allocator refuses to hold
// ~128 floats/thread (VGPR_Count=84, arrays in scratch, ~160 scratch
// ops/iter = issue-bound). Fix: x,y live in LDS (16384 x float2 =
// 128KB, ds_read_b64, 2-way bank alias = free); only z[16]+dist[16]
// stay in registers (~55-reg demand). Each thread reads back its own
// points, so no barrier needed in the distance loop; one barrier per
// iteration for the argmax exchange (parity double-buffered table).
// fp contract OFF so fp32 matches numpy exactly (argmax cascade).
// ------------------------------------------------------------------
__global__ __launch_bounds__(1024, 4) void fused_front_kernel(
    const float* __restrict__ xyz, const float* __restrict__ feat,
    const float* __restrict__ W1, const float* __restrict__ W2,
    const float* __restrict__ W3, float* __restrict__ WT,
    float* __restrict__ featT, float* __restrict__ newxyz) {
  __shared__ __align__(16) char raw[131072];  // sxy (FPS) / tile (transpose)
  __shared__ float s_val[2][16];
  __shared__ int s_idx[2][16];
  const int blk = blockIdx.x;
  const int t = threadIdx.x;

  if (blk < 8) {
#pragma clang fp contract(off)
    const int b = blk;
    const float* xb = xyz + (size_t)b * NPTS * 3;
    float* nb = newxyz + (size_t)b * NPOINT * 3;
    v2f* sxy = (v2f*)raw;  // 16384 x float2 = 128KB
    float z[16], dist[16];
#pragma unroll
    for (int k = 0; k < 16; ++k) {
      const int p = (k << 10) | t;
      v2f xy;
      xy.x = xb[p * 3 + 0];
      xy.y = xb[p * 3 + 1];
      z[k] = xb[p * 3 + 2];
      dist[k] = 1e10f;
      sxy[p] = xy;
    }
    __syncthreads();  // fill -> broadcast reads
    v2f lxy = sxy[0];
    float lz = xb[2];
    if (t == 0) { nb[0] = lxy.x; nb[1] = lxy.y; nb[2] = lz; }
    const int w = t >> 6;
    const int lane = t & 63;
    for (int j = 1; j < NPOINT; ++j) {
      float bestv = -1.0f;
      int bestK = 0;
#pragma unroll
      for (int k = 0; k < 16; ++k) {
        v2f pxy = sxy[(k << 10) | t];  // own write, no barrier needed
        v2f d2v = pxy - lxy;
        d2v = d2v * d2v;               // contract off: pk_mul exact
        float dz = z[k] - lz;
        float d = d2v.x + d2v.y;       // dx^2+dy^2 first, like numpy
        d = d + dz * dz;
        float nd = fminf(dist[k], d);
        dist[k] = nd;
        if (nd > bestv) { bestv = nd; bestK = k; }  // strict >: smallest k wins
      }
      int besti = (bestK << 10) | t;
      // wave-64 argmax butterfly, smallest-index tie break
#pragma unroll
      for (int off = 1; off < 64; off <<= 1) {
        float ov = __shfl_xor(bestv, off);
        int oi = __shfl_xor(besti, off);
        if (ov > bestv || (ov == bestv && oi < besti)) { bestv = ov; besti = oi; }
      }
      const int pw = j & 1;
      if (lane == 0) { s_val[pw][w] = bestv; s_idx[pw][w] = besti; }
      __syncthreads();
      // every wave reduces the 16 wave-bests (replicated across lanes)
      float v = s_val[pw][lane & 15];
      int vi = s_idx[pw][lane & 15];
#pragma unroll
      for (int off = 1; off < 16; off <<= 1) {
        float ov = __shfl_xor(v, off);
        int oi = __shfl_xor(vi, off);
        if (ov > v || (ov == v && oi < vi)) { v = ov; vi = oi; }
      }
      const int wi = __builtin_amdgcn_readfirstlane(vi);
      lxy = sxy[wi];           // LDS broadcast
      lz = xb[(size_t)wi * 3 + 2];  // uniform -> scalar load
      if (t == 0) { float* o = nb + j * 3; o[0] = lxy.x; o[1] = lxy.y; o[2] = lz; }
    }
  } else if (blk == 8) {
    // weight transposes: W*T[c][o] = W*[o][c]
    float* W1T = WT;                      // 67 x 64
    float* W2T = WT + 67 * 64;            // 64 x 64
    float* W3T = WT + 67 * 64 + 64 * 64;  // 64 x 128
    for (int i = t; i < 64 * 67; i += 1024) { int o = i / 67, c = i - o * 67; W1T[c * 64 + o] = W1[i]; }
    for (int i = t; i < 64 * 64; i += 1024) { int o = i >> 6, c = i & 63; W2T[c * 64 + o] = W2[i]; }
    for (int i = t; i < 128 * 64; i += 1024) { int o = i >> 6, c = i & 63; W3T[c * 128 + o] = W3[i]; }
  } else {
    // feature transpose: one 64(ch) x 128(pt) stripe per block
    float (*tile)[129] = (float(*)[129])raw;  // 64 x 129 x 4B = 33KB
    const int tid = blk - 9;
    const int b = tid >> 7;
    const int n0 = (tid & 127) << 7;
    const int col = t & 127;
    const int row = t >> 7;  // 0..7
#pragma unroll
    for (int k = 0; k < 8; ++k) {
      int c = k * 8 + row;
      tile[c][col] = feat[((size_t)b * CFEAT + c) * NPTS + n0 + col];
    }
    __syncthreads();
    const int cc = t & 63;
#pragma unroll
    for (int k = 0; k < 8; ++k) {
      int nl = (t >> 6) + 16 * k;  // 0..127
      featT[((size_t)b * NPTS + n0 + nl) * CFEAT + cc] = tile[cc][nl];
    }
  }
}

// ------------------------------------------------------------------
// Ball query: 1 wave per query, 4 queries per 256-thread block.
// Scans all N points in index order via LDS tiles; ballot-compacts the
// first 32 indices with d2 <= r^2; pads remainder with first index.
// ------------------------------------------------------------------
__global__ __launch_bounds__(256) void ballquery_kernel(const float* __restrict__ xyz,
                                                        const float* __restrict__ newxyz,
                                                        int* __restrict__ idxout) {
#pragma clang fp contract(off)
  const int blk = blockIdx.x;
  const int b = blk >> 8;  // 256 blocks per batch
  const int t = threadIdx.x;
  const int w = t >> 6;
  const int lane = t & 63;
  const int q = ((blk & 255) << 2) | w;
  const int g = b * NPOINT + q;
  const float* xb = xyz + (size_t)b * NPTS * 3;
  const float qx = newxyz[(size_t)g * 3 + 0];
  const float qy = newxyz[(size_t)g * 3 + 1];
  const float qz = newxyz[(size_t)g * 3 + 2];
  __shared__ __align__(16) float lds[2048 * 3];
  int total = 0;
  int first = 0;
  const unsigned long long ltmask = (1ull << lane) - 1ull;
  for (int T = 0; T < 8; ++T) {
    __syncthreads();
    const float4* src = (const float4*)(xb + (size_t)T * 2048 * 3);
#pragma unroll
    for (int k = 0; k < 6; ++k) ((float4*)lds)[t + 256 * k] = src[t + 256 * k];
    __syncthreads();
    if (total < NSAMPLE) {
      for (int c = 0; c < 32; ++c) {
        const int il = (c << 6) | lane;
        float dx = lds[il * 3 + 0] - qx;
        float dy = lds[il * 3 + 1] - qy;
        float dz = lds[il * 3 + 2] - qz;
        float d2 = dx * dx + dy * dy;
        d2 = d2 + dz * dz;
        const bool within = d2 <= RADIUS2;
        const unsigned long long mask = __ballot(within);
        if (total == 0 && mask != 0ull)
          first = (T << 11) | (c << 6) | (__ffsll((unsigned long long)mask) - 1);
        if (within) {
          int pos = total + __popcll(mask & ltmask);
          if (pos < NSAMPLE) idxout[(size_t)g * NSAMPLE + pos] = (T << 11) | il;
        }
        total += __popcll(mask);
        if (total >= NSAMPLE) break;
      }
    }
  }
  if (total < NSAMPLE) {
    if (lane >= total && lane < NSAMPLE) idxout[(size_t)g * NSAMPLE + lane] = first;
  }
}

// ------------------------------------------------------------------
// Gather + 3-layer pointwise MLP + max over 32 samples. One block per
// group (b,q): 256 threads = 32 samples x 8 lanes. Hidden activations
// staged in LDS (padded strides 69/132 -> conflict-free).
// ------------------------------------------------------------------
template <bool USE_FEATT>
__global__ __launch_bounds__(256) void mlp_kernel(const float* __restrict__ xyz,
                                                  const float* __restrict__ feat,
                                                  const float* __restrict__ featT,
                                                  const float* __restrict__ newxyz,
                                                  const int* __restrict__ idx,
                                                  const float* __restrict__ WT,
                                                  const float* __restrict__ b1,
                                                  const float* __restrict__ b2,
                                                  const float* __restrict__ b3,
                                                  float* __restrict__ outfeat) {
  const int g = blockIdx.x;
  const int b = g >> 10;
  const int q = g & 1023;
  const int t = threadIdx.x;
  const int s = t >> 3;
  const int u = t & 7;
  __shared__ float in_s[32][69];
  __shared__ float h1_s[32][69];
  __shared__ float h2_s[32][69];
  __shared__ float h3_s[32][132];
  const float* W1T = WT;
  const float* W2T = WT + 67 * 64;
  const float* W3T = WT + 67 * 64 + 64 * 64;

  const int gi = idx[(size_t)g * NSAMPLE + s];
  if (u == 0) {
    const float* p = xyz + ((size_t)b * NPTS + gi) * 3;
    const float* c = newxyz + (size_t)g * 3;
    in_s[s][0] = p[0] - c[0];
    in_s[s][1] = p[1] - c[1];
    in_s[s][2] = p[2] - c[2];
  }
  if (USE_FEATT) {
    const float* fr = featT + ((size_t)b * NPTS + gi) * CFEAT + u * 8;
    float4 a = *(const float4*)fr;
    float4 c4 = *(const float4*)(fr + 4);
    in_s[s][3 + u * 8 + 0] = a.x;  in_s[s][3 + u * 8 + 1] = a.y;
    in_s[s][3 + u * 8 + 2] = a.z;  in_s[s][3 + u * 8 + 3] = a.w;
    in_s[s][3 + u * 8 + 4] = c4.x; in_s[s][3 + u * 8 + 5] = c4.y;
    in_s[s][3 + u * 8 + 6] = c4.z; in_s[s][3 + u * 8 + 7] = c4.w;
  } else {
#pragma unroll
    for (int k = 0; k < 8; ++k)
      in_s[s][3 + u * 8 + k] = feat[((size_t)b * CFEAT + u * 8 + k) * NPTS + gi];
  }
  __syncthreads();
  {  // layer 1: 67 -> 64
    float acc[8];
    const int o0 = u * 8;
#pragma unroll
    for (int k = 0; k < 8; ++k) acc[k] = b1[o0 + k];
    for (int c = 0; c < 67; ++c) {
      float x = in_s[s][c];
      const float* wp = W1T + c * 64 + o0;
      float4 w0 = *(const float4*)wp;
      float4 w1 = *(const float4*)(wp + 4);
      acc[0] += w0.x * x; acc[1] += w0.y * x; acc[2] += w0.z * x; acc[3] += w0.w * x;
      acc[4] += w1.x * x; acc[5] += w1.y * x; acc[6] += w1.z * x; acc[7] += w1.w * x;
    }
#pragma unroll
    for (int k = 0; k < 8; ++k) h1_s[s][o0 + k] = fmaxf(acc[k], 0.0f);
  }
  __syncthreads();
  {  // layer 2: 64 -> 64
    float acc[8];
    const int o0 = u * 8;
#pragma unroll
    for (int k = 0; k < 8; ++k) acc[k] = b2[o0 + k];
    for (int c = 0; c < 64; ++c) {
      float x = h1_s[s][c];
      const float* wp = W2T + c * 64 + o0;
      float4 w0 = *(const float4*)wp;
      float4 w1 = *(const float4*)(wp + 4);
      acc[0] += w0.x * x; acc[1] += w0.y * x; acc[2] += w0.z * x; acc[3] += w0.w * x;
      acc[4] += w1.x * x; acc[5] += w1.y * x; acc[6] += w1.z * x; acc[7] += w1.w * x;
    }
#pragma unroll
    for (int k = 0; k < 8; ++k) h2_s[s][o0 + k] = fmaxf(acc[k], 0.0f);
  }
  __syncthreads();
  {  // layer 3: 64 -> 128
    float acc[16];
    const int o0 = u * 16;
#pragma unroll
    for (int k = 0; k < 16; ++k) acc[k] = b3[o0 + k];
    for (int c = 0; c < 64; ++c) {
      float x = h2_s[s][c];
      const float* wp = W3T + c * 128 + o0;
      float4 w0 = *(const float4*)wp;
      float4 w1 = *(const float4*)(wp + 4);
      float4 w2 = *(const float4*)(wp + 8);
      float4 w3 = *(const float4*)(wp + 12);
      acc[0] += w0.x * x;  acc[1] += w0.y * x;  acc[2] += w0.z * x;  acc[3] += w0.w * x;
      acc[4] += w1.x * x;  acc[5] += w1.y * x;  acc[6] += w1.z * x;  acc[7] += w1.w * x;
      acc[8] += w2.x * x;  acc[9] += w2.y * x;  acc[10] += w2.z * x; acc[11] += w2.w * x;
      acc[12] += w3.x * x; acc[13] += w3.y * x; acc[14] += w3.z * x; acc[15] += w3.w * x;
    }
#pragma unroll
    for (int k = 0; k < 16; ++k) h3_s[s][o0 + k] = fmaxf(acc[k], 0.0f);
  }
  __syncthreads();
  if (t < 128) {
    float m = h3_s[0][t];
#pragma unroll 4
    for (int ss = 1; ss < 32; ++ss) m = fmaxf(m, h3_s[ss][t]);
    outfeat[((size_t)b * 128 + t) * NPOINT + q] = m;
  }
}

extern "C" void kernel_launch(void* const* d_in, const int* in_sizes, int n_in,
                              void* d_out, int out_size, void* d_ws, size_t ws_size,
                              hipStream_t stream) {
  const float* xyz = (const float*)d_in[0];
  const float* features = (const float*)d_in[1];
  const float* W1 = (const float*)d_in[2];
  const float* b1 = (const float*)d_in[3];
  const float* W2 = (const float*)d_in[4];
  const float* b2 = (const float*)d_in[5];
  const float* W3 = (const float*)d_in[6];
  const float* b3 = (const float*)d_in[7];
  float* out_newxyz = (float*)d_out;                          // B*NPOINT*3
  float* out_feat = (float*)d_out + (size_t)BQ * NPOINT * 3;  // B*128*NPOINT

  char* ws = (char*)d_ws;
  int* idx = (int*)ws;                              // 1 MB
  float* WT = (float*)(ws + (1 << 20));             // 66304 B
  float* featT = (float*)(ws + (1 << 20) + 66560);  // 32 MB
  const size_t need = (size_t)(1 << 20) + 66560 + (size_t)BQ * NPTS * CFEAT * 4;
  const bool useT = ws_size >= need;

  const int nfront = useT ? (9 + (NPTS / 128) * BQ) : 9;
  hipLaunchKernelGGL(fused_front_kernel, dim3(nfront), dim3(1024), 0, stream,
                     xyz, features, W1, W2, W3, WT, featT, out_newxyz);
  hipLaunchKernelGGL(ballquery_kernel, dim3(BQ * NPOINT / 4), dim3(256), 0, stream,
                     xyz, out_newxyz, idx);
  if (useT)
    hipLaunchKernelGGL(mlp_kernel<true>, dim3(BQ * NPOINT), dim3(256), 0, stream,
                       xyz, features, featT, out_newxyz, idx, WT, b1, b2, b3, out_feat);
  else
    hipLaunchKernelGGL(mlp_kernel<false>, dim3(BQ * NPOINT), dim3(256), 0, stream,
                       xyz, features, featT, out_newxyz, idx, WT, b1, b2, b3, out_feat);
}

// Round 7
// 2938.435 us; speedup vs baseline: 1.1319x; 1.1319x over previous
//
#include <hip/hip_runtime.h>

#define BQ 8
#define NPTS 16384
#define CFEAT 64
#define NPOINT 1024
#define NSAMPLE 32
#define RADIUS2 0.04f

typedef float v2f __attribute__((ext_vector_type(2)));

// DPP-based lexicographic max of (key_hi, key_lo) carrying z.
// update_dpp(old, src, ctrl, row_mask, bank_mask, bound_ctrl=false):
// invalid/masked lanes keep `old` (= own value) -> harmless no-op compare.
template <int CTRL, int RMASK>
__device__ __forceinline__ void dpp_max3(unsigned& hi, unsigned& lo, float& zz) {
  unsigned ohi = (unsigned)__builtin_amdgcn_update_dpp((int)hi, (int)hi, CTRL, RMASK, 0xf, false);
  unsigned olo = (unsigned)__builtin_amdgcn_update_dpp((int)lo, (int)lo, CTRL, RMASK, 0xf, false);
  int oz = __builtin_amdgcn_update_dpp(__float_as_int(zz), __float_as_int(zz), CTRL, RMASK, 0xf, false);
  unsigned long long ok = (((unsigned long long)ohi) << 32) | olo;
  unsigned long long ck = (((unsigned long long)hi) << 32) | lo;
  if (ok > ck) { hi = ohi; lo = olo; zz = __int_as_float(oz); }
}

// ------------------------------------------------------------------
// Fused front kernel, 1024 threads/block:
//   blocks 0..7    : furthest point sampling (1 block per batch)
//   block  8       : weight transpose prep
//   blocks 9..1032 : features (B,C,N) -> featT (B,N,C) transpose
// FPS v5 (round-6 post-mortem: ~4400 of 5790 cyc/iter was serial tail
// -- ds_bpermute shuffle chains + barrier skew + winner global load).
//   * x,y in LDS as SoA (64KB+64KB), z+dist in regs as v2f pairs
//     (consecutive even/odd points per thread -> v_pk_* distance math)
//   * argmax via u64 key (bits(dist)<<32 | 16384-idx): monotone for
//     dist>=0, tie -> smaller idx; reduced with VALU-only DPP network
//     row_shr 1/2/4/8 + bcast15(0xa) + bcast31(0xc) -> lane 63
//   * winner z carried through the DPP compare (3rd reg) -> no global
//     fetch on the critical path; x,y via uniform LDS broadcast
//   * one barrier/iter, parity double-buffered 16-entry wave table
// fp contract OFF so fp32 matches numpy exactly (argmax cascade).
// ------------------------------------------------------------------
__global__ __launch_bounds__(1024, 4) void fused_front_kernel(
    const float* __restrict__ xyz, const float* __restrict__ feat,
    const float* __restrict__ W1, const float* __restrict__ W2,
    const float* __restrict__ W3, float* __restrict__ WT,
    float* __restrict__ featT, float* __restrict__ newxyz) {
  __shared__ __align__(16) char raw[131072];  // FPS: sx|sy ; transpose: tile
  __shared__ uint4 s_tab[2][16];
  const int blk = blockIdx.x;
  const int t = threadIdx.x;

  if (blk < 8) {
#pragma clang fp contract(off)
    const int b = blk;
    const float* xb = xyz + (size_t)b * NPTS * 3;
    float* nb = newxyz + (size_t)b * NPOINT * 3;
    float* sx = (float*)raw;            // 16384 floats
    float* sy = (float*)(raw + 65536);  // 16384 floats
    v2f* sx2 = (v2f*)sx;
    v2f* sy2 = (v2f*)sy;
    v2f zc[8], dd[8];
    // fill: thread t owns point pairs p0=(k<<11)|(t<<1), p1=p0+1
#pragma unroll
    for (int k = 0; k < 8; ++k) {
      const int p0 = (k << 11) | (t << 1);
      v2f xv, yv, zv, d0;
      xv.x = xb[p0 * 3 + 0]; xv.y = xb[p0 * 3 + 3];
      yv.x = xb[p0 * 3 + 1]; yv.y = xb[p0 * 3 + 4];
      zv.x = xb[p0 * 3 + 2]; zv.y = xb[p0 * 3 + 5];
      d0.x = 1e10f; d0.y = 1e10f;
      sx2[(k << 10) | t] = xv;
      sy2[(k << 10) | t] = yv;
      zc[k] = zv;
      dd[k] = d0;
    }
    float wx = xb[0], wy = xb[1], wz = xb[2];
    if (t == 0) { nb[0] = wx; nb[1] = wy; nb[2] = wz; }
    const int w = t >> 6;
    const int lane = t & 63;
    __syncthreads();  // LDS fill visible
    for (int j = 1; j < NPOINT; ++j) {
      v2f lx2, ly2, lz2;
      lx2.x = wx; lx2.y = wx;
      ly2.x = wy; ly2.y = wy;
      lz2.x = wz; lz2.y = wz;
      float bestv = -1.0f, bestz = 0.0f;
      int bestK = 0;
#pragma unroll
      for (int k = 0; k < 8; ++k) {
        v2f xv = sx2[(k << 10) | t];
        v2f yv = sy2[(k << 10) | t];
        v2f dx = xv - lx2;
        v2f dy = yv - ly2;
        v2f dz = zc[k] - lz2;
        v2f sxx = dx * dx;
        v2f syy = dy * dy;
        v2f sxy = sxx + syy;       // dx^2+dy^2 first, like numpy
        v2f szz = dz * dz;
        v2f d = sxy + szz;
        float n0 = fminf(dd[k].x, d.x);
        float n1 = fminf(dd[k].y, d.y);
        v2f nd; nd.x = n0; nd.y = n1;
        dd[k] = nd;
        if (n0 > bestv) { bestv = n0; bestK = 2 * k; bestz = zc[k].x; }      // strict >:
        if (n1 > bestv) { bestv = n1; bestK = 2 * k + 1; bestz = zc[k].y; }  // smallest idx wins
      }
      // pack u64 key: hi = bits(dist>=0) monotone; lo = 16384-idx (tie -> min idx)
      const int gidx = ((bestK >> 1) << 11) | (t << 1) | (bestK & 1);
      unsigned hi = __float_as_uint(bestv);
      unsigned lo = (unsigned)(16384 - gidx);
      float bz = bestz;
      dpp_max3<0x111, 0xf>(hi, lo, bz);  // row_shr:1
      dpp_max3<0x112, 0xf>(hi, lo, bz);  // row_shr:2
      dpp_max3<0x114, 0xf>(hi, lo, bz);  // row_shr:4
      dpp_max3<0x118, 0xf>(hi, lo, bz);  // row_shr:8  -> lane15/31/47/63 = row max
      dpp_max3<0x142, 0xa>(hi, lo, bz);  // bcast15 rows 1,3 -> lane31=0..31, lane63=32..63
      dpp_max3<0x143, 0xc>(hi, lo, bz);  // bcast31 rows 2,3 -> lane63 = all 64
      const int pw = j & 1;
      if (lane == 63) {
        uint4 e; e.x = hi; e.y = lo; e.z = __float_as_uint(bz); e.w = 0;
        s_tab[pw][w] = e;
      }
      __syncthreads();
      // cross-wave: 16 entries, lane-replicated, 4 row-DPP steps -> lane15
      uint4 e = s_tab[pw][lane & 15];
      unsigned hi2 = e.x, lo2 = e.y;
      float z2 = __uint_as_float(e.z);
      dpp_max3<0x111, 0xf>(hi2, lo2, z2);
      dpp_max3<0x112, 0xf>(hi2, lo2, z2);
      dpp_max3<0x114, 0xf>(hi2, lo2, z2);
      dpp_max3<0x118, 0xf>(hi2, lo2, z2);
      const int wlo = __builtin_amdgcn_readlane((int)lo2, 15);
      wz = __int_as_float(__builtin_amdgcn_readlane(__float_as_int(z2), 15));
      const int wi = 16384 - wlo;
      wx = sx[wi];  // uniform address -> LDS broadcast
      wy = sy[wi];
      if (t == 0) { float* o = nb + j * 3; o[0] = wx; o[1] = wy; o[2] = wz; }
    }
  } else if (blk == 8) {
    // weight transposes: W*T[c][o] = W*[o][c]
    float* W1T = WT;                      // 67 x 64
    float* W2T = WT + 67 * 64;            // 64 x 64
    float* W3T = WT + 67 * 64 + 64 * 64;  // 64 x 128
    for (int i = t; i < 64 * 67; i += 1024) { int o = i / 67, c = i - o * 67; W1T[c * 64 + o] = W1[i]; }
    for (int i = t; i < 64 * 64; i += 1024) { int o = i >> 6, c = i & 63; W2T[c * 64 + o] = W2[i]; }
    for (int i = t; i < 128 * 64; i += 1024) { int o = i >> 6, c = i & 63; W3T[c * 128 + o] = W3[i]; }
  } else {
    // feature transpose: one 64(ch) x 128(pt) stripe per block
    float (*tile)[129] = (float(*)[129])raw;  // 64 x 129 x 4B = 33KB
    const int tid = blk - 9;
    const int b = tid >> 7;
    const int n0 = (tid & 127) << 7;
    const int col = t & 127;
    const int row = t >> 7;  // 0..7
#pragma unroll
    for (int k = 0; k < 8; ++k) {
      int c = k * 8 + row;
      tile[c][col] = feat[((size_t)b * CFEAT + c) * NPTS + n0 + col];
    }
    __syncthreads();
    const int cc = t & 63;
#pragma unroll
    for (int k = 0; k < 8; ++k) {
      int nl = (t >> 6) + 16 * k;  // 0..127
      featT[((size_t)b * NPTS + n0 + nl) * CFEAT + cc] = tile[cc][nl];
    }
  }
}

// ------------------------------------------------------------------
// Ball query: 1 wave per query, 4 queries per 256-thread block.
// Scans all N points in index order via LDS tiles; ballot-compacts the
// first 32 indices with d2 <= r^2; pads remainder with first index.
// ------------------------------------------------------------------
__global__ __launch_bounds__(256) void ballquery_kernel(const float* __restrict__ xyz,
                                                        const float* __restrict__ newxyz,
                                                        int* __restrict__ idxout) {
#pragma clang fp contract(off)
  const int blk = blockIdx.x;
  const int b = blk >> 8;  // 256 blocks per batch
  const int t = threadIdx.x;
  const int w = t >> 6;
  const int lane = t & 63;
  const int q = ((blk & 255) << 2) | w;
  const int g = b * NPOINT + q;
  const float* xb = xyz + (size_t)b * NPTS * 3;
  const float qx = newxyz[(size_t)g * 3 + 0];
  const float qy = newxyz[(size_t)g * 3 + 1];
  const float qz = newxyz[(size_t)g * 3 + 2];
  __shared__ __align__(16) float lds[2048 * 3];
  int total = 0;
  int first = 0;
  const unsigned long long ltmask = (1ull << lane) - 1ull;
  for (int T = 0; T < 8; ++T) {
    __syncthreads();
    const float4* src = (const float4*)(xb + (size_t)T * 2048 * 3);
#pragma unroll
    for (int k = 0; k < 6; ++k) ((float4*)lds)[t + 256 * k] = src[t + 256 * k];
    __syncthreads();
    if (total < NSAMPLE) {
      for (int c = 0; c < 32; ++c) {
        const int il = (c << 6) | lane;
        float dx = lds[il * 3 + 0] - qx;
        float dy = lds[il * 3 + 1] - qy;
        float dz = lds[il * 3 + 2] - qz;
        float d2 = dx * dx + dy * dy;
        d2 = d2 + dz * dz;
        const bool within = d2 <= RADIUS2;
        const unsigned long long mask = __ballot(within);
        if (total == 0 && mask != 0ull)
          first = (T << 11) | (c << 6) | (__ffsll((unsigned long long)mask) - 1);
        if (within) {
          int pos = total + __popcll(mask & ltmask);
          if (pos < NSAMPLE) idxout[(size_t)g * NSAMPLE + pos] = (T << 11) | il;
        }
        total += __popcll(mask);
        if (total >= NSAMPLE) break;
      }
    }
  }
  if (total < NSAMPLE) {
    if (lane >= total && lane < NSAMPLE) idxout[(size_t)g * NSAMPLE + lane] = first;
  }
}

// ------------------------------------------------------------------
// Gather + 3-layer pointwise MLP + max over 32 samples. One block per
// group (b,q): 256 threads = 32 samples x 8 lanes. Hidden activations
// staged in LDS (padded strides 69/132 -> conflict-free).
// ------------------------------------------------------------------
template <bool USE_FEATT>
__global__ __launch_bounds__(256) void mlp_kernel(const float* __restrict__ xyz,
                                                  const float* __restrict__ feat,
                                                  const float* __restrict__ featT,
                                                  const float* __restrict__ newxyz,
                                                  const int* __restrict__ idx,
                                                  const float* __restrict__ WT,
                                                  const float* __restrict__ b1,
                                                  const float* __restrict__ b2,
                                                  const float* __restrict__ b3,
                                                  float* __restrict__ outfeat) {
  const int g = blockIdx.x;
  const int b = g >> 10;
  const int q = g & 1023;
  const int t = threadIdx.x;
  const int s = t >> 3;
  const int u = t & 7;
  __shared__ float in_s[32][69];
  __shared__ float h1_s[32][69];
  __shared__ float h2_s[32][69];
  __shared__ float h3_s[32][132];
  const float* W1T = WT;
  const float* W2T = WT + 67 * 64;
  const float* W3T = WT + 67 * 64 + 64 * 64;

  const int gi = idx[(size_t)g * NSAMPLE + s];
  if (u == 0) {
    const float* p = xyz + ((size_t)b * NPTS + gi) * 3;
    const float* c = newxyz + (size_t)g * 3;
    in_s[s][0] = p[0] - c[0];
    in_s[s][1] = p[1] - c[1];
    in_s[s][2] = p[2] - c[2];
  }
  if (USE_FEATT) {
    const float* fr = featT + ((size_t)b * NPTS + gi) * CFEAT + u * 8;
    float4 a = *(const float4*)fr;
    float4 c4 = *(const float4*)(fr + 4);
    in_s[s][3 + u * 8 + 0] = a.x;  in_s[s][3 + u * 8 + 1] = a.y;
    in_s[s][3 + u * 8 + 2] = a.z;  in_s[s][3 + u * 8 + 3] = a.w;
    in_s[s][3 + u * 8 + 4] = c4.x; in_s[s][3 + u * 8 + 5] = c4.y;
    in_s[s][3 + u * 8 + 6] = c4.z; in_s[s][3 + u * 8 + 7] = c4.w;
  } else {
#pragma unroll
    for (int k = 0; k < 8; ++k)
      in_s[s][3 + u * 8 + k] = feat[((size_t)b * CFEAT + u * 8 + k) * NPTS + gi];
  }
  __syncthreads();
  {  // layer 1: 67 -> 64
    float acc[8];
    const int o0 = u * 8;
#pragma unroll
    for (int k = 0; k < 8; ++k) acc[k] = b1[o0 + k];
    for (int c = 0; c < 67; ++c) {
      float x = in_s[s][c];
      const float* wp = W1T + c * 64 + o0;
      float4 w0 = *(const float4*)wp;
      float4 w1 = *(const float4*)(wp + 4);
      acc[0] += w0.x * x; acc[1] += w0.y * x; acc[2] += w0.z * x; acc[3] += w0.w * x;
      acc[4] += w1.x * x; acc[5] += w1.y * x; acc[6] += w1.z * x; acc[7] += w1.w * x;
    }
#pragma unroll
    for (int k = 0; k < 8; ++k) h1_s[s][o0 + k] = fmaxf(acc[k], 0.0f);
  }
  __syncthreads();
  {  // layer 2: 64 -> 64
    float acc[8];
    const int o0 = u * 8;
#pragma unroll
    for (int k = 0; k < 8; ++k) acc[k] = b2[o0 + k];
    for (int c = 0; c < 64; ++c) {
      float x = h1_s[s][c];
      const float* wp = W2T + c * 64 + o0;
      float4 w0 = *(const float4*)wp;
      float4 w1 = *(const float4*)(wp + 4);
      acc[0] += w0.x * x; acc[1] += w0.y * x; acc[2] += w0.z * x; acc[3] += w0.w * x;
      acc[4] += w1.x * x; acc[5] += w1.y * x; acc[6] += w1.z * x; acc[7] += w1.w * x;
    }
#pragma unroll
    for (int k = 0; k < 8; ++k) h2_s[s][o0 + k] = fmaxf(acc[k], 0.0f);
  }
  __syncthreads();
  {  // layer 3: 64 -> 128
    float acc[16];
    const int o0 = u * 16;
#pragma unroll
    for (int k = 0; k < 16; ++k) acc[k] = b3[o0 + k];
    for (int c = 0; c < 64; ++c) {
      float x = h2_s[s][c];
      const float* wp = W3T + c * 128 + o0;
      float4 w0 = *(const float4*)wp;
      float4 w1 = *(const float4*)(wp + 4);
      float4 w2 = *(const float4*)(wp + 8);
      float4 w3 = *(const float4*)(wp + 12);
      acc[0] += w0.x * x;  acc[1] += w0.y * x;  acc[2] += w0.z * x;  acc[3] += w0.w * x;
      acc[4] += w1.x * x;  acc[5] += w1.y * x;  acc[6] += w1.z * x;  acc[7] += w1.w * x;
      acc[8] += w2.x * x;  acc[9] += w2.y * x;  acc[10] += w2.z * x; acc[11] += w2.w * x;
      acc[12] += w3.x * x; acc[13] += w3.y * x; acc[14] += w3.z * x; acc[15] += w3.w * x;
    }
#pragma unroll
    for (int k = 0; k < 16; ++k) h3_s[s][o0 + k] = fmaxf(acc[k], 0.0f);
  }
  __syncthreads();
  if (t < 128) {
    float m = h3_s[0][t];
#pragma unroll 4
    for (int ss = 1; ss < 32; ++ss) m = fmaxf(m, h3_s[ss][t]);
    outfeat[((size_t)b * 128 + t) * NPOINT + q] = m;
  }
}

extern "C" void kernel_launch(void* const* d_in, const int* in_sizes, int n_in,
                              void* d_out, int out_size, void* d_ws, size_t ws_size,
                              hipStream_t stream) {
  const float* xyz = (const float*)d_in[0];
  const float* features = (const float*)d_in[1];
  const float* W1 = (const float*)d_in[2];
  const float* b1 = (const float*)d_in[3];
  const float* W2 = (const float*)d_in[4];
  const float* b2 = (const float*)d_in[5];
  const float* W3 = (const float*)d_in[6];
  const float* b3 = (const float*)d_in[7];
  float* out_newxyz = (float*)d_out;                          // B*NPOINT*3
  float* out_feat = (float*)d_out + (size_t)BQ * NPOINT * 3;  // B*128*NPOINT

  char* ws = (char*)d_ws;
  int* idx = (int*)ws;                              // 1 MB
  float* WT = (float*)(ws + (1 << 20));             // 66304 B
  float* featT = (float*)(ws + (1 << 20) + 66560);  // 32 MB
  const size_t need = (size_t)(1 << 20) + 66560 + (size_t)BQ * NPTS * CFEAT * 4;
  const bool useT = ws_size >= need;

  const int nfront = useT ? (9 + (NPTS / 128) * BQ) : 9;
  hipLaunchKernelGGL(fused_front_kernel, dim3(nfront), dim3(1024), 0, stream,
                     xyz, features, W1, W2, W3, WT, featT, out_newxyz);
  hipLaunchKernelGGL(ballquery_kernel, dim3(BQ * NPOINT / 4), dim3(256), 0, stream,
                     xyz, out_newxyz, idx);
  if (useT)
    hipLaunchKernelGGL(mlp_kernel<true>, dim3(BQ * NPOINT), dim3(256), 0, stream,
                       xyz, features, featT, out_newxyz, idx, WT, b1, b2, b3, out_feat);
  else
    hipLaunchKernelGGL(mlp_kernel<false>, dim3(BQ * NPOINT), dim3(256), 0, stream,
                       xyz, features, featT, out_newxyz, idx, WT, b1, b2, b3, out_feat);
}

// Round 11
// 2576.203 us; speedup vs baseline: 1.2910x; 1.1406x over previous
//
#include <hip/hip_runtime.h>

#define BQ 8
#define NPTS 16384
#define CFEAT 64
#define NPOINT 1024
#define NSAMPLE 32
#define RADIUS2 0.04f

typedef float v2f __attribute__((ext_vector_type(2)));

// DPP lexicographic max of (hi,lo) as exact u64 compare.
// update_dpp(old, src, ctrl, row_mask, bank_mask, bound_ctrl=false):
// masked/invalid lanes keep own value -> harmless no-op compare.
template <int CTRL, int RMASK>
__device__ __forceinline__ void dpp_max2(unsigned& hi, unsigned& lo) {
  unsigned ohi = (unsigned)__builtin_amdgcn_update_dpp((int)hi, (int)hi, CTRL, RMASK, 0xf, false);
  unsigned olo = (unsigned)__builtin_amdgcn_update_dpp((int)lo, (int)lo, CTRL, RMASK, 0xf, false);
  unsigned long long ok = (((unsigned long long)ohi) << 32) | olo;
  unsigned long long ck = (((unsigned long long)hi) << 32) | lo;
  if (ok > ck) { hi = ohi; lo = olo; }
}

// ------------------------------------------------------------------
// Fused front kernel, 512 threads/block:
//   blocks 0..7    : furthest point sampling (1 block per batch)
//   block  8       : weight transpose prep
//   blocks 9..2056 : features (B,C,N) -> featT (B,N,C) transpose
// FPS v6 (round-7 post-mortem: VALU-issue-bound at ~94% on active CUs).
//   * x,y in LDS SoA (64KB+64KB); z + dist in regs (16 v2f each)
//   * k-loop tracking via f64-packed key: hi=bits(dist) (dist>=0 ->
//     positive-double order == u64 order), lo=16384-idx (tie -> min
//     idx). Per element: v_min_f32 + v_max_f64. No cndmask chains.
//   * reduction carries only (hi,lo): 6-stage wave DPP + 8-entry
//     cross-wave stage via parity-double-buffered LDS table; winner z
//     re-fetched with a uniform scalar load (off the issue path).
//   * 512 thr = 2 waves/SIMD: same issue cost as 1024, half the
//     barrier/stage-2 overhead; ~110 VGPR demand well under (512,1) cap.
// fp contract OFF so fp32 matches numpy exactly (argmax cascade).
// ------------------------------------------------------------------
__global__ __launch_bounds__(512, 1) void fused_front_kernel(
    const float* __restrict__ xyz, const float* __restrict__ feat,
    const float* __restrict__ W1, const float* __restrict__ W2,
    const float* __restrict__ W3, float* __restrict__ WT,
    float* __restrict__ featT, float* __restrict__ newxyz) {
  __shared__ __align__(16) char raw[131072];  // FPS: sx|sy ; transpose: tile
  __shared__ uint2 s_tab[2][8];
  const int blk = blockIdx.x;
  const int t = threadIdx.x;

  if (blk < 8) {
#pragma clang fp contract(off)
    const int b = blk;
    const float* xb = xyz + (size_t)b * NPTS * 3;
    float* nb = newxyz + (size_t)b * NPOINT * 3;
    float* sx = (float*)raw;            // 16384 floats
    float* sy = (float*)(raw + 65536);  // 16384 floats
    v2f* sx2 = (v2f*)sx;
    v2f* sy2 = (v2f*)sy;
    v2f zc[16], dd[16];
    // fill: thread t owns pairs pi=(k<<9)|t -> points 2*pi, 2*pi+1
#pragma unroll
    for (int k = 0; k < 16; ++k) {
      const int pi = (k << 9) | t;
      const v2f* pp = (const v2f*)(xb + (size_t)(pi << 1) * 3);
      v2f a = pp[0], bb = pp[1], c = pp[2];  // {x0,y0} {z0,x1} {y1,z1}
      v2f xv, yv, zv, d0;
      xv.x = a.x;  xv.y = bb.y;
      yv.x = a.y;  yv.y = c.x;
      zv.x = bb.x; zv.y = c.y;
      d0.x = 1e10f; d0.y = 1e10f;
      sx2[pi] = xv;
      sy2[pi] = yv;
      zc[k] = zv;
      dd[k] = d0;
    }
    float wx = xb[0], wy = xb[1], wz = xb[2];
    if (t == 0) { nb[0] = wx; nb[1] = wy; nb[2] = wz; }
    const int w = t >> 6;
    const int lane = t & 63;
    __syncthreads();  // LDS fill visible
    for (int j = 1; j < NPOINT; ++j) {
      v2f lx2, ly2, lz2;
      lx2.x = wx; lx2.y = wx;
      ly2.x = wy; ly2.y = wy;
      lz2.x = wz; lz2.y = wz;
      double best = -1.0;  // < every valid key (keys >= 0)
#pragma unroll
      for (int k = 0; k < 16; ++k) {
        v2f xv = sx2[(k << 9) | t];
        v2f yv = sy2[(k << 9) | t];
        v2f dx = xv - lx2;
        v2f dy = yv - ly2;
        v2f dz = zc[k] - lz2;
        v2f s1 = dx * dx;
        v2f s2 = dy * dy;
        v2f s3 = s1 + s2;        // dx^2+dy^2 first, like numpy
        v2f s4 = dz * dz;
        v2f d = s3 + s4;
        float n0 = fminf(dd[k].x, d.x);
        float n1 = fminf(dd[k].y, d.y);
        v2f nd; nd.x = n0; nd.y = n1;
        dd[k] = nd;
        const int i0 = (k << 10) | (t << 1);
        // key: hi=bits(dist) (>=0 -> monotone), lo=16384-idx (tie->min idx)
        double c0 = __hiloint2double(__float_as_int(n0), 16384 - i0);
        double c1 = __hiloint2double(__float_as_int(n1), 16383 - i0);
        best = fmax(best, c0);
        best = fmax(best, c1);
      }
      unsigned hi = (unsigned)__double2hiint(best);
      unsigned lo = (unsigned)__double2loint(best);
      // wave-64 max (exact u64 compares), result -> lane 63
      dpp_max2<0x111, 0xf>(hi, lo);  // row_shr:1
      dpp_max2<0x112, 0xf>(hi, lo);  // row_shr:2
      dpp_max2<0x114, 0xf>(hi, lo);  // row_shr:4
      dpp_max2<0x118, 0xf>(hi, lo);  // row_shr:8
      dpp_max2<0x142, 0xa>(hi, lo);  // bcast15 rows 1,3
      dpp_max2<0x143, 0xc>(hi, lo);  // bcast31 rows 2,3
      const int pw = j & 1;
      if (lane == 63) { uint2 e; e.x = hi; e.y = lo; s_tab[pw][w] = e; }
      __syncthreads();
      // cross-wave: 8 entries, lane-replicated, 3 row-DPP steps -> lane7
      uint2 e = s_tab[pw][lane & 7];
      unsigned hi2 = e.x, lo2 = e.y;
      dpp_max2<0x111, 0xf>(hi2, lo2);
      dpp_max2<0x112, 0xf>(hi2, lo2);
      dpp_max2<0x114, 0xf>(hi2, lo2);
      const int wlo = __builtin_amdgcn_readlane((int)lo2, 7);
      const int wi = 16384 - wlo;
      wz = xb[(size_t)wi * 3 + 2];  // uniform -> scalar load (off issue path)
      wx = sx[wi];                  // uniform LDS broadcast
      wy = sy[wi];
      if (t == 0) { float* o = nb + j * 3; o[0] = wx; o[1] = wy; o[2] = wz; }
    }
  } else if (blk == 8) {
    // weight transposes: W*T[c][o] = W*[o][c]
    float* W1T = WT;                      // 67 x 64
    float* W2T = WT + 67 * 64;            // 64 x 64
    float* W3T = WT + 67 * 64 + 64 * 64;  // 64 x 128
    for (int i = t; i < 64 * 67; i += 512) { int o = i / 67, c = i - o * 67; W1T[c * 64 + o] = W1[i]; }
    for (int i = t; i < 64 * 64; i += 512) { int o = i >> 6, c = i & 63; W2T[c * 64 + o] = W2[i]; }
    for (int i = t; i < 128 * 64; i += 512) { int o = i >> 6, c = i & 63; W3T[c * 128 + o] = W3[i]; }
  } else {
    // feature transpose: one 64x64 tile per block
    float (*tile)[65] = (float(*)[65])raw;  // 64 x 65 x 4B = 16.6KB
    const int tid = blk - 9;
    const int b = tid >> 8;
    const int n0 = (tid & 255) << 6;
    const int col = t & 63;
    const int row = t >> 6;  // 0..7
#pragma unroll
    for (int k = 0; k < 8; ++k) {
      int c = k * 8 + row;
      tile[c][col] = feat[((size_t)b * CFEAT + c) * NPTS + n0 + col];
    }
    __syncthreads();
#pragma unroll
    for (int k = 0; k < 8; ++k) {
      int nl = k * 8 + row;
      featT[((size_t)b * NPTS + n0 + nl) * CFEAT + col] = tile[col][nl];
    }
  }
}

// ------------------------------------------------------------------
// Ball query: 1 wave per query, 4 queries per 256-thread block.
// Scans all N points in index order via LDS tiles; ballot-compacts the
// first 32 indices with d2 <= r^2; pads remainder with first index.
// ------------------------------------------------------------------
__global__ __launch_bounds__(256) void ballquery_kernel(const float* __restrict__ xyz,
                                                        const float* __restrict__ newxyz,
                                                        int* __restrict__ idxout) {
#pragma clang fp contract(off)
  const int blk = blockIdx.x;
  const int b = blk >> 8;  // 256 blocks per batch
  const int t = threadIdx.x;
  const int w = t >> 6;
  const int lane = t & 63;
  const int q = ((blk & 255) << 2) | w;
  const int g = b * NPOINT + q;
  const float* xb = xyz + (size_t)b * NPTS * 3;
  const float qx = newxyz[(size_t)g * 3 + 0];
  const float qy = newxyz[(size_t)g * 3 + 1];
  const float qz = newxyz[(size_t)g * 3 + 2];
  __shared__ __align__(16) float lds[2048 * 3];
  int total = 0;
  int first = 0;
  const unsigned long long ltmask = (1ull << lane) - 1ull;
  for (int T = 0; T < 8; ++T) {
    __syncthreads();
    const float4* src = (const float4*)(xb + (size_t)T * 2048 * 3);
#pragma unroll
    for (int k = 0; k < 6; ++k) ((float4*)lds)[t + 256 * k] = src[t + 256 * k];
    __syncthreads();
    if (total < NSAMPLE) {
      for (int c = 0; c < 32; ++c) {
        const int il = (c << 6) | lane;
        float dx = lds[il * 3 + 0] - qx;
        float dy = lds[il * 3 + 1] - qy;
        float dz = lds[il * 3 + 2] - qz;
        float d2 = dx * dx + dy * dy;
        d2 = d2 + dz * dz;
        const bool within = d2 <= RADIUS2;
        const unsigned long long mask = __ballot(within);
        if (total == 0 && mask != 0ull)
          first = (T << 11) | (c << 6) | (__ffsll((unsigned long long)mask) - 1);
        if (within) {
          int pos = total + __popcll(mask & ltmask);
          if (pos < NSAMPLE) idxout[(size_t)g * NSAMPLE + pos] = (T << 11) | il;
        }
        total += __popcll(mask);
        if (total >= NSAMPLE) break;
      }
    }
  }
  if (total < NSAMPLE) {
    if (lane >= total && lane < NSAMPLE) idxout[(size_t)g * NSAMPLE + lane] = first;
  }
}

// ------------------------------------------------------------------
// Gather + 3-layer pointwise MLP + max over 32 samples. One block per
// group (b,q): 256 threads = 32 samples x 8 lanes. Hidden activations
// staged in LDS (padded strides 69/132 -> conflict-free).
// ------------------------------------------------------------------
template <bool USE_FEATT>
__global__ __launch_bounds__(256) void mlp_kernel(const float* __restrict__ xyz,
                                                  const float* __restrict__ feat,
                                                  const float* __restrict__ featT,
                                                  const float* __restrict__ newxyz,
                                                  const int* __restrict__ idx,
                                                  const float* __restrict__ WT,
                                                  const float* __restrict__ b1,
                                                  const float* __restrict__ b2,
                                                  const float* __restrict__ b3,
                                                  float* __restrict__ outfeat) {
  const int g = blockIdx.x;
  const int b = g >> 10;
  const int q = g & 1023;
  const int t = threadIdx.x;
  const int s = t >> 3;
  const int u = t & 7;
  __shared__ float in_s[32][69];
  __shared__ float h1_s[32][69];
  __shared__ float h2_s[32][69];
  __shared__ float h3_s[32][132];
  const float* W1T = WT;
  const float* W2T = WT + 67 * 64;
  const float* W3T = WT + 67 * 64 + 64 * 64;

  const int gi = idx[(size_t)g * NSAMPLE + s];
  if (u == 0) {
    const float* p = xyz + ((size_t)b * NPTS + gi) * 3;
    const float* c = newxyz + (size_t)g * 3;
    in_s[s][0] = p[0] - c[0];
    in_s[s][1] = p[1] - c[1];
    in_s[s][2] = p[2] - c[2];
  }
  if (USE_FEATT) {
    const float* fr = featT + ((size_t)b * NPTS + gi) * CFEAT + u * 8;
    float4 a = *(const float4*)fr;
    float4 c4 = *(const float4*)(fr + 4);
    in_s[s][3 + u * 8 + 0] = a.x;  in_s[s][3 + u * 8 + 1] = a.y;
    in_s[s][3 + u * 8 + 2] = a.z;  in_s[s][3 + u * 8 + 3] = a.w;
    in_s[s][3 + u * 8 + 4] = c4.x; in_s[s][3 + u * 8 + 5] = c4.y;
    in_s[s][3 + u * 8 + 6] = c4.z; in_s[s][3 + u * 8 + 7] = c4.w;
  } else {
#pragma unroll
    for (int k = 0; k < 8; ++k)
      in_s[s][3 + u * 8 + k] = feat[((size_t)b * CFEAT + u * 8 + k) * NPTS + gi];
  }
  __syncthreads();
  {  // layer 1: 67 -> 64
    float acc[8];
    const int o0 = u * 8;
#pragma unroll
    for (int k = 0; k < 8; ++k) acc[k] = b1[o0 + k];
    for (int c = 0; c < 67; ++c) {
      float x = in_s[s][c];
      const float* wp = W1T + c * 64 + o0;
      float4 w0 = *(const float4*)wp;
      float4 w1 = *(const float4*)(wp + 4);
      acc[0] += w0.x * x; acc[1] += w0.y * x; acc[2] += w0.z * x; acc[3] += w0.w * x;
      acc[4] += w1.x * x; acc[5] += w1.y * x; acc[6] += w1.z * x; acc[7] += w1.w * x;
    }
#pragma unroll
    for (int k = 0; k < 8; ++k) h1_s[s][o0 + k] = fmaxf(acc[k], 0.0f);
  }
  __syncthreads();
  {  // layer 2: 64 -> 64
    float acc[8];
    const int o0 = u * 8;
#pragma unroll
    for (int k = 0; k < 8; ++k) acc[k] = b2[o0 + k];
    for (int c = 0; c < 64; ++c) {
      float x = h1_s[s][c];
      const float* wp = W2T + c * 64 + o0;
      float4 w0 = *(const float4*)wp;
      float4 w1 = *(const float4*)(wp + 4);
      acc[0] += w0.x * x; acc[1] += w0.y * x; acc[2] += w0.z * x; acc[3] += w0.w * x;
      acc[4] += w1.x * x; acc[5] += w1.y * x; acc[6] += w1.z * x; acc[7] += w1.w * x;
    }
#pragma unroll
    for (int k = 0; k < 8; ++k) h2_s[s][o0 + k] = fmaxf(acc[k], 0.0f);
  }
  __syncthreads();
  {  // layer 3: 64 -> 128
    float acc[16];
    const int o0 = u * 16;
#pragma unroll
    for (int k = 0; k < 16; ++k) acc[k] = b3[o0 + k];
    for (int c = 0; c < 64; ++c) {
      float x = h2_s[s][c];
      const float* wp = W3T + c * 128 + o0;
      float4 w0 = *(const float4*)wp;
      float4 w1 = *(const float4*)(wp + 4);
      float4 w2 = *(const float4*)(wp + 8);
      float4 w3 = *(const float4*)(wp + 12);
      acc[0] += w0.x * x;  acc[1] += w0.y * x;  acc[2] += w0.z * x;  acc[3] += w0.w * x;
      acc[4] += w1.x * x;  acc[5] += w1.y * x;  acc[6] += w1.z * x;  acc[7] += w1.w * x;
      acc[8] += w2.x * x;  acc[9] += w2.y * x;  acc[10] += w2.z * x; acc[11] += w2.w * x;
      acc[12] += w3.x * x; acc[13] += w3.y * x; acc[14] += w3.z * x; acc[15] += w3.w * x;
    }
#pragma unroll
    for (int k = 0; k < 16; ++k) h3_s[s][o0 + k] = fmaxf(acc[k], 0.0f);
  }
  __syncthreads();
  if (t < 128) {
    float m = h3_s[0][t];
#pragma unroll 4
    for (int ss = 1; ss < 32; ++ss) m = fmaxf(m, h3_s[ss][t]);
    outfeat[((size_t)b * 128 + t) * NPOINT + q] = m;
  }
}

extern "C" void kernel_launch(void* const* d_in, const int* in_sizes, int n_in,
                              void* d_out, int out_size, void* d_ws, size_t ws_size,
                              hipStream_t stream) {
  const float* xyz = (const float*)d_in[0];
  const float* features = (const float*)d_in[1];
  const float* W1 = (const float*)d_in[2];
  const float* b1 = (const float*)d_in[3];
  const float* W2 = (const float*)d_in[4];
  const float* b2 = (const float*)d_in[5];
  const float* W3 = (const float*)d_in[6];
  const float* b3 = (const float*)d_in[7];
  float* out_newxyz = (float*)d_out;                          // B*NPOINT*3
  float* out_feat = (float*)d_out + (size_t)BQ * NPOINT * 3;  // B*128*NPOINT

  char* ws = (char*)d_ws;
  int* idx = (int*)ws;                              // 1 MB
  float* WT = (float*)(ws + (1 << 20));             // 66304 B
  float* featT = (float*)(ws + (1 << 20) + 66560);  // 32 MB
  const size_t need = (size_t)(1 << 20) + 66560 + (size_t)BQ * NPTS * CFEAT * 4;
  const bool useT = ws_size >= need;

  const int nfront = useT ? (9 + (NPTS / 64) * BQ) : 9;
  hipLaunchKernelGGL(fused_front_kernel, dim3(nfront), dim3(512), 0, stream,
                     xyz, features, W1, W2, W3, WT, featT, out_newxyz);
  hipLaunchKernelGGL(ballquery_kernel, dim3(BQ * NPOINT / 4), dim3(256), 0, stream,
                     xyz, out_newxyz, idx);
  if (useT)
    hipLaunchKernelGGL(mlp_kernel<true>, dim3(BQ * NPOINT), dim3(256), 0, stream,
                       xyz, features, featT, out_newxyz, idx, WT, b1, b2, b3, out_feat);
  else
    hipLaunchKernelGGL(mlp_kernel<false>, dim3(BQ * NPOINT), dim3(256), 0, stream,
                       xyz, features, featT, out_newxyz, idx, WT, b1, b2, b3, out_feat);
}